// Round 9
// baseline (241.066 us; speedup 1.0000x reference)
//
#include <hip/hip_runtime.h>
#include <hip/hip_bf16.h>

// RNN-T Joiner. N=8 T=512 U=64 J=512 V=500 (padded 512).
// ws: enc_p bf16 [4096,512] | dec_p bf16 [512,512] | wimg bf16 frag-ordered (512KB) | bpad
// prep (273 blocks): conv_wout (128) | enc proj (128) | dec proj (16) | bpad (1)
// joiner: 512 thr / 8 waves, BM=64, BN=512, BK=32, wave 64m x 64v, mfma 32x32x16.
//   B: global_load_lds (issued 1 kt ahead, frag-ordered identity copy) -> LDS dbuf 2x32KB.
//   A: tanh-staged 4KB LDS dbuf. Epilogue: 2 rounds x 32 rows via 66KB LDS (aliases B).
//   launch_bounds(512,4) -> <=128 VGPR -> 2 blocks/CU (LDS 74KB/block).

typedef __attribute__((ext_vector_type(4))) float f32x4;
typedef __attribute__((ext_vector_type(16))) float f32x16;
typedef __attribute__((ext_vector_type(4))) short s16x4;
typedef __attribute__((ext_vector_type(8))) short s16x8;
typedef __attribute__((ext_vector_type(4))) unsigned short u16x4;

static __device__ __forceinline__ unsigned short f2bf(float x) {
    union { float f; unsigned u; } v; v.f = x;
    return (unsigned short)((v.u + 0x7FFFu + ((v.u >> 16) & 1u)) >> 16);  // RNE
}

static __device__ __forceinline__ float bf2f(unsigned short u) {
    union { unsigned u; float f; } v; v.u = ((unsigned)u) << 16;
    return v.f;
}

static __device__ __forceinline__ float fast_tanh(float x) {
    float e = __expf(2.0f * x);
    float r = __builtin_amdgcn_rcpf(e + 1.0f);
    return __builtin_fmaf(-2.0f, r, 1.0f);
}

#define GLOAD16(gsrc, ldst)                                                  \
    __builtin_amdgcn_global_load_lds(                                        \
        (const __attribute__((address_space(1))) unsigned int*)(gsrc),       \
        (__attribute__((address_space(3))) unsigned int*)(ldst), 16, 0, 0)

// 64B-row swizzle: row r, 16B-slot c; byte = r*64 + ((c ^ ((r>>1)&3)) << 4)
static __device__ __forceinline__ unsigned swz64(int r, int c) {
    return (unsigned)(r * 64 + ((c ^ ((r >> 1) & 3)) << 4));
}

// ---------------- projection GEMM body (verified; bf16 output) ----------------
static __device__ void proj_body(
    const float* __restrict__ A, const float* __restrict__ W,
    const float* __restrict__ b, unsigned short* __restrict__ C,
    int mt, int jt, unsigned short* As, unsigned short* Bs)
{
    const int tid = threadIdx.x;
    const int lane = tid & 63, wid = tid >> 6;
    const int wm = wid >> 1, wn = wid & 1;

    f32x4 acc[4][4];
    const f32x4 zero = {0.f, 0.f, 0.f, 0.f};
    #pragma unroll
    for (int i = 0; i < 4; ++i)
        #pragma unroll
        for (int j = 0; j < 4; ++j) acc[i][j] = zero;

    const int c8 = (tid & 7) * 8;
    const int rbase = tid >> 3;

    for (int kt = 0; kt < 8; ++kt) {
        __syncthreads();
        #pragma unroll
        for (int p = 0; p < 4; ++p) {
            int r = p * 32 + rbase;
            int byte = (r * 128 + c8 * 2) ^ ((r & 7) << 4);
            {
                const float* s = A + (size_t)(mt * 128 + r) * 512 + kt * 64 + c8;
                f32x4 v0 = *(const f32x4*)s, v1 = *(const f32x4*)(s + 4);
                s16x8 pk;
                pk[0] = (short)f2bf(v0[0]); pk[1] = (short)f2bf(v0[1]);
                pk[2] = (short)f2bf(v0[2]); pk[3] = (short)f2bf(v0[3]);
                pk[4] = (short)f2bf(v1[0]); pk[5] = (short)f2bf(v1[1]);
                pk[6] = (short)f2bf(v1[2]); pk[7] = (short)f2bf(v1[3]);
                *(s16x8*)((char*)As + byte) = pk;
            }
            {
                const float* s = W + (size_t)(jt * 128 + r) * 512 + kt * 64 + c8;
                f32x4 v0 = *(const f32x4*)s, v1 = *(const f32x4*)(s + 4);
                s16x8 pk;
                pk[0] = (short)f2bf(v0[0]); pk[1] = (short)f2bf(v0[1]);
                pk[2] = (short)f2bf(v0[2]); pk[3] = (short)f2bf(v0[3]);
                pk[4] = (short)f2bf(v1[0]); pk[5] = (short)f2bf(v1[1]);
                pk[6] = (short)f2bf(v1[2]); pk[7] = (short)f2bf(v1[3]);
                *(s16x8*)((char*)Bs + byte) = pk;
            }
        }
        __syncthreads();
        #pragma unroll
        for (int kk = 0; kk < 2; ++kk) {
            s16x8 af[4], bfr[4];
            #pragma unroll
            for (int mi = 0; mi < 4; ++mi) {
                int row = wm * 64 + mi * 16 + (lane & 15);
                int byte = (row * 128 + kk * 64 + ((lane >> 4) * 16)) ^ ((row & 7) << 4);
                af[mi] = *(const s16x8*)((const char*)As + byte);
            }
            #pragma unroll
            for (int ni = 0; ni < 4; ++ni) {
                int row = wn * 64 + ni * 16 + (lane & 15);
                int byte = (row * 128 + kk * 64 + ((lane >> 4) * 16)) ^ ((row & 7) << 4);
                bfr[ni] = *(const s16x8*)((const char*)Bs + byte);
            }
            #pragma unroll
            for (int mi = 0; mi < 4; ++mi)
                #pragma unroll
                for (int ni = 0; ni < 4; ++ni)
                    acc[mi][ni] = __builtin_amdgcn_mfma_f32_16x16x32_bf16(
                        af[mi], bfr[ni], acc[mi][ni], 0, 0, 0);
        }
    }

    #pragma unroll
    for (int ni = 0; ni < 4; ++ni) {
        int col = jt * 128 + wn * 64 + ni * 16 + (lane & 15);
        float bias = b[col];
        #pragma unroll
        for (int mi = 0; mi < 4; ++mi) {
            int row0 = mt * 128 + wm * 64 + mi * 16 + ((lane >> 4) << 2);
            #pragma unroll
            for (int j = 0; j < 4; ++j)
                C[(size_t)(row0 + j) * 512 + col] = f2bf(acc[mi][ni][j] + bias);
        }
    }
}

// ---------------- fused prep: conv_wout | enc proj | dec proj | bpad ----------------
__global__ __launch_bounds__(256) void prep(
    const float* __restrict__ Wout, unsigned short* __restrict__ img,
    const float* __restrict__ encoder_out, const float* __restrict__ W_enc,
    const float* __restrict__ b_enc, unsigned short* __restrict__ enc_p,
    const float* __restrict__ decoder_out, const float* __restrict__ W_dec,
    const float* __restrict__ b_dec, unsigned short* __restrict__ dec_p,
    const float* __restrict__ b_out, float* __restrict__ bpad)
{
    __shared__ unsigned short As[128 * 64];
    __shared__ unsigned short Bs[128 * 64];
    const int b = blockIdx.x;
    if (b < 128) {
        // W_out -> bf16 per-lane MFMA-fragment-ordered image (verified layout):
        // chunk tid = ((kt*16+tile)*2+khalf)*64+lane -> 8 bf16 of
        //   W[v=tile*32+(lane&31)][k=kt*32+khalf*16+(lane>>5)*8 + j], v>=500 -> 0
        int tid = b * 256 + threadIdx.x;
        int lane = tid & 63;
        int khalf = (tid >> 6) & 1;
        int tile = (tid >> 7) & 15;
        int kt = tid >> 11;
        int v = tile * 32 + (lane & 31);
        int k = kt * 32 + khalf * 16 + (lane >> 5) * 8;
        s16x8 pk = {0, 0, 0, 0, 0, 0, 0, 0};
        if (v < 500) {
            const float* s = Wout + (size_t)v * 512 + k;
            f32x4 a = *(const f32x4*)s, c = *(const f32x4*)(s + 4);
            pk[0] = (short)f2bf(a[0]); pk[1] = (short)f2bf(a[1]);
            pk[2] = (short)f2bf(a[2]); pk[3] = (short)f2bf(a[3]);
            pk[4] = (short)f2bf(c[0]); pk[5] = (short)f2bf(c[1]);
            pk[6] = (short)f2bf(c[2]); pk[7] = (short)f2bf(c[3]);
        }
        *(s16x8*)(img + (size_t)tid * 8) = pk;
    } else if (b < 256) {
        int q = b - 128;                       // enc proj: M=4096
        proj_body(encoder_out, W_enc, b_enc, enc_p, q & 31, q >> 5, As, Bs);
    } else if (b < 272) {
        int q = b - 256;                       // dec proj: M=512
        proj_body(decoder_out, W_dec, b_dec, dec_p, q & 3, q >> 2, As, Bs);
    } else {
        int i = threadIdx.x;                   // bpad: 512-padded bias
        bpad[i] = (i < 500) ? b_out[i] : 0.f;
        bpad[i + 256] = (i + 256 < 500) ? b_out[i + 256] : 0.f;
    }
}

// ---------------- fused tanh + vocab GEMM ----------------
__global__ __launch_bounds__(512, 4) void joiner_main(
    const unsigned short* __restrict__ enc, const unsigned short* __restrict__ dec,
    const unsigned short* __restrict__ Wimg, const float* __restrict__ bout,
    float* __restrict__ out)
{
    __shared__ __align__(16) char raw[74240];
    unsigned short* As0 = (unsigned short*)raw;            // 4 KB [64 r][32 k] swizzled
    unsigned short* As1 = (unsigned short*)(raw + 4096);   // 4 KB
    char* Bs0 = raw + 8192;                                // 32 KB frag-ordered kt slice
    char* Bs1 = raw + 40960;                               // 32 KB
    float* ep = (float*)(raw + 8192);                      // epilogue [32][516] f32 (aliases B)

    const int bid = blockIdx.x;                 // bid = n*512 + t
    const int tid = threadIdx.x, lane = tid & 63, wn = tid >> 6;  // 8 waves across V
    const int n = bid >> 9, t = bid & 511;

    f32x16 acc[2][2];
    #pragma unroll
    for (int i = 0; i < 2; ++i)
        #pragma unroll
        for (int j = 0; j < 2; ++j)
            #pragma unroll
            for (int e = 0; e < 16; ++e) acc[i][j][e] = 0.f;

    // A staging: thread -> row r = tid>>3 (u 0..63), 8B chunk q = tid&7 (k = q*4..+3)
    const int r = tid >> 3;
    const int q = tid & 7;
    const unsigned short* erow = enc + ((size_t)n * 512 + t) * 512 + q * 4;
    const unsigned short* drow = dec + ((size_t)n * 64 + r) * 512 + q * 4;
    const unsigned abyte = swz64(r, q >> 1) + (q & 1) * 8;
    // B staging: identity copy of 32KB kt slice; thread copies 4 x 16B.
    // gload_lds: LDS dst must be wave-uniform base (HW adds lane*16); src is per-lane.
    const char* bsrc = (const char*)Wimg + (size_t)wn * 1024 + (size_t)lane * 16;
    const int bdoff = wn * 1024;
    // B frag read offsets (within 32KB slice): wn*4096 + ni*2048 + kh*1024 + lane*16
    const int boff = wn * 4096 + lane * 16;
    const int lr = lane & 31, kg = lane >> 5;

    // ---- prologue: stage A(kt0), issue B(kt0) ----
    {
        u16x4 e = *(const u16x4*)erow;
        u16x4 d = *(const u16x4*)drow;
        s16x4 p;
        p[0] = (short)f2bf(fast_tanh(bf2f(e[0]) + bf2f(d[0])));
        p[1] = (short)f2bf(fast_tanh(bf2f(e[1]) + bf2f(d[1])));
        p[2] = (short)f2bf(fast_tanh(bf2f(e[2]) + bf2f(d[2])));
        p[3] = (short)f2bf(fast_tanh(bf2f(e[3]) + bf2f(d[3])));
        *(s16x4*)((char*)As0 + abyte) = p;
        #pragma unroll
        for (int i = 0; i < 4; ++i)
            GLOAD16(bsrc + i * 8192, Bs0 + bdoff + i * 8192);
    }
    __syncthreads();

    #pragma unroll
    for (int kt = 0; kt < 16; ++kt) {
        const char* Ac = (char*)((kt & 1) ? As1 : As0);
        char* An = (char*)((kt & 1) ? As0 : As1);
        const char* Bc = (kt & 1) ? Bs1 : Bs0;
        char* Bn = (kt & 1) ? Bs0 : Bs1;

        // 1. issue next B slice ASAP (completes during tanh+ds_read+MFMA; barrier drains)
        if (kt < 15) {
            const char* g = bsrc + (size_t)(kt + 1) * 32768;
            #pragma unroll
            for (int i = 0; i < 4; ++i)
                GLOAD16(g + i * 8192, Bn + bdoff + i * 8192);
        }
        // 2. stage next A tile (tanh VALU overlaps MFMA pipe)
        if (kt < 15) {
            u16x4 e = *(const u16x4*)(erow + (kt + 1) * 32);
            u16x4 d = *(const u16x4*)(drow + (kt + 1) * 32);
            s16x4 p;
            p[0] = (short)f2bf(fast_tanh(bf2f(e[0]) + bf2f(d[0])));
            p[1] = (short)f2bf(fast_tanh(bf2f(e[1]) + bf2f(d[1])));
            p[2] = (short)f2bf(fast_tanh(bf2f(e[2]) + bf2f(d[2])));
            p[3] = (short)f2bf(fast_tanh(bf2f(e[3]) + bf2f(d[3])));
            *(s16x4*)(An + abyte) = p;
        }
        // 3. per-kh fragment reads (all LDS, conflict-free) + MFMA
        #pragma unroll
        for (int kh = 0; kh < 2; ++kh) {
            s16x8 b0 = *(const s16x8*)(Bc + boff + 0 * 2048 + kh * 1024);
            s16x8 b1 = *(const s16x8*)(Bc + boff + 1 * 2048 + kh * 1024);
            s16x8 a0 = *(const s16x8*)(Ac + swz64(lr, kh * 2 + kg));
            s16x8 a1 = *(const s16x8*)(Ac + swz64(32 + lr, kh * 2 + kg));
            acc[0][0] = __builtin_amdgcn_mfma_f32_32x32x16_bf16(b0, a0, acc[0][0], 0, 0, 0);
            acc[0][1] = __builtin_amdgcn_mfma_f32_32x32x16_bf16(b1, a0, acc[0][1], 0, 0, 0);
            acc[1][0] = __builtin_amdgcn_mfma_f32_32x32x16_bf16(b0, a1, acc[1][0], 0, 0, 0);
            acc[1][1] = __builtin_amdgcn_mfma_f32_32x32x16_bf16(b1, a1, acc[1][1], 0, 0, 0);
        }
        __syncthreads();
    }

    // ---- epilogue: 2 rounds of 32 rows; LDS transpose -> linear NT streams ----
    // acc[mi][ni][reg]: m = mi*32 + (lane&31),
    //                   v = wn*64 + ni*32 + (reg&3) + 8*(reg>>2) + 4*(lane>>5)
    const int hi4 = (lane >> 5) * 4;
    #pragma unroll
    for (int o = 0; o < 2; ++o) {
        if (o) __syncthreads();
        {
            const int mi = o;
            #pragma unroll
            for (int ni = 0; ni < 2; ++ni) {
                #pragma unroll
                for (int qq = 0; qq < 4; ++qq) {
                    int v4 = wn * 64 + ni * 32 + qq * 8 + hi4;
                    if (v4 < 500) {
                        f32x4 b = *(const f32x4*)(bout + v4);   // bout 512-padded
                        f32x4 ov;
                        ov[0] = acc[mi][ni][qq * 4 + 0] + b[0];
                        ov[1] = acc[mi][ni][qq * 4 + 1] + b[1];
                        ov[2] = acc[mi][ni][qq * 4 + 2] + b[2];
                        ov[3] = acc[mi][ni][qq * 4 + 3] + b[3];
                        *(f32x4*)(ep + lr * 516 + v4) = ov;
                    }
                }
            }
        }
        __syncthreads();
        const size_t obase = ((size_t)bid * 64 + o * 32) * 500;
        #pragma unroll
        for (int i = 0; i < 8; ++i) {
            int idx = i * 512 + tid;                    // f32x4 chunk, 4000 total
            if (idx < 4000) {
                int rr = idx / 125;
                int vi = (idx - rr * 125) * 4;
                f32x4 ov = *(const f32x4*)(ep + rr * 516 + vi);
                __builtin_nontemporal_store(ov, (f32x4*)(out + obase + (size_t)idx * 4));
            }
        }
    }
}

extern "C" void kernel_launch(void* const* d_in, const int* in_sizes, int n_in,
                              void* d_out, int out_size, void* d_ws, size_t ws_size,
                              hipStream_t stream) {
    const float* encoder_out = (const float*)d_in[0];  // [8,512,512]
    const float* decoder_out = (const float*)d_in[1];  // [8,64,512]
    const float* W_enc = (const float*)d_in[2];
    const float* b_enc = (const float*)d_in[3];
    const float* W_dec = (const float*)d_in[4];
    const float* b_dec = (const float*)d_in[5];
    const float* W_out = (const float*)d_in[6];        // [500,512]
    const float* b_out = (const float*)d_in[7];        // [500]
    float* out = (float*)d_out;                        // [8,512,64,500]

    unsigned short* enc_p = (unsigned short*)d_ws;              // 4 MB bf16
    unsigned short* dec_p = enc_p + (size_t)4096 * 512;         // 512 KB bf16
    unsigned short* wimg  = dec_p + (size_t)512 * 512;          // 512 KB bf16
    float* bpad = (float*)(wimg + 262144);                      // 2 KB f32

    prep<<<dim3(273), 256, 0, stream>>>(W_out, wimg,
                                        encoder_out, W_enc, b_enc, enc_p,
                                        decoder_out, W_dec, b_dec, dec_p,
                                        b_out, bpad);
    joiner_main<<<dim3(4096), 512, 0, stream>>>(enc_p, dec_p, wimg, bpad, out);
}